// Round 1
// baseline (1779.789 us; speedup 1.0000x reference)
//
#include <hip/hip_runtime.h>

// HiPPO-LegT forward scan, fp32.
//   c_t = c_{t-1} @ A^T + f_t * B    (per sequence; 512 sequences, N=256, L=1024)
// Layout decisions:
//  - 256 workgroups x 1024 threads, 2 sequences per WG (1 WG/CU on 256 CUs).
//  - A (256KB fp32) is register-resident: thread (row, cb) holds A[row, cb*64 .. +64)
//    = 64 VGPRs. This is the only placement with enough bandwidth (LDS can't fit
//    fp32 A; L2 streaming would be ~17TB).
//  - c lives in LDS, double-buffered, padded stride 68 floats per 64-block so the
//    4 distinct ds_read_b128 addresses per wave hit disjoint bank groups.
//  - quad-lane shfl_xor reduction (lanes 4r..4r+3 are the 4 col-blocks of row r).

#define LSTEPS 1024
#define CPAD 68

__global__ __launch_bounds__(1024, 4) void hippo_legt_kernel(
    const float* __restrict__ inp,   // (512, 1024) = (B*M, L), contiguous in t
    const float* __restrict__ A,     // (256, 256) row-major (discrete Ad)
    const float* __restrict__ Bvec,  // (256)      (discrete Bd)
    float* __restrict__ out)         // (1024, 512, 256)
{
    __shared__ __attribute__((aligned(16))) float cbuf[2][2][4][CPAD]; // [buf][seq][blk][pad]
    __shared__ __attribute__((aligned(16))) float fbuf[2][LSTEPS];

    const int tid  = threadIdx.x;
    const int row  = tid >> 2;   // 0..255
    const int cb   = tid & 3;    // col-block 0..3
    const int seq0 = blockIdx.x * 2;

    // A fragment: A[row][cb*64 + k], k = 0..63, as 16 float4 (64 VGPRs).
    float4 a[16];
    {
        const float4* Ar = reinterpret_cast<const float4*>(A + row * 256 + cb * 64);
        #pragma unroll
        for (int k = 0; k < 16; ++k) a[k] = Ar[k];
    }
    const float bd = Bvec[row];

    // Preload f for both sequences: 2048 floats = 512 float4, coalesced.
    if (tid < 512) {
        reinterpret_cast<float4*>(&fbuf[0][0])[tid] =
            reinterpret_cast<const float4*>(inp + (size_t)seq0 * LSTEPS)[tid];
    }
    // Zero initial state buffer (buf 0).
    if (tid < 2 * 4 * CPAD) {
        (&cbuf[0][0][0][0])[tid] = 0.0f;
    }
    __syncthreads();

    float* outp = out + (size_t)seq0 * 256 + row;

    auto step = [&](int cur, int nxt, int t) {
        const float f0 = fbuf[0][t];               // wave-uniform LDS broadcast
        const float f1 = fbuf[1][t];
        const float4* c0 = reinterpret_cast<const float4*>(&cbuf[cur][0][cb][0]);
        const float4* c1 = reinterpret_cast<const float4*>(&cbuf[cur][1][cb][0]);
        float4 s0 = make_float4(0.f, 0.f, 0.f, 0.f);
        float4 s1 = make_float4(0.f, 0.f, 0.f, 0.f);
        #pragma unroll
        for (int k = 0; k < 16; ++k) {
            const float4 v0 = c0[k];
            const float4 v1 = c1[k];
            s0.x = fmaf(a[k].x, v0.x, s0.x);
            s0.y = fmaf(a[k].y, v0.y, s0.y);
            s0.z = fmaf(a[k].z, v0.z, s0.z);
            s0.w = fmaf(a[k].w, v0.w, s0.w);
            s1.x = fmaf(a[k].x, v1.x, s1.x);
            s1.y = fmaf(a[k].y, v1.y, s1.y);
            s1.z = fmaf(a[k].z, v1.z, s1.z);
            s1.w = fmaf(a[k].w, v1.w, s1.w);
        }
        float p0 = (s0.x + s0.y) + (s0.z + s0.w);
        float p1 = (s1.x + s1.y) + (s1.z + s1.w);
        // reduce the 4 col-block partials (lanes 4r..4r+3)
        p0 += __shfl_xor(p0, 1);  p0 += __shfl_xor(p0, 2);
        p1 += __shfl_xor(p1, 1);  p1 += __shfl_xor(p1, 2);
        const float cn0 = fmaf(bd, f0, p0);
        const float cn1 = fmaf(bd, f1, p1);
        if (cb == 0) {
            cbuf[nxt][0][row >> 6][row & 63] = cn0;
            cbuf[nxt][1][row >> 6][row & 63] = cn1;
            float* o = outp + (size_t)t * (512 * 256);
            o[0]   = cn0;   // seq0,   state `row` at time t
            o[256] = cn1;   // seq0+1, state `row` at time t
        }
        __syncthreads();
    };

    for (int t = 0; t < LSTEPS; t += 2) {
        step(0, 1, t);       // read buf0 -> write buf1
        step(1, 0, t + 1);   // read buf1 -> write buf0
    }
}

extern "C" void kernel_launch(void* const* d_in, const int* in_sizes, int n_in,
                              void* d_out, int out_size, void* d_ws, size_t ws_size,
                              hipStream_t stream) {
    const float* inp = (const float*)d_in[0];   // (8,64,1024) fp32
    const float* A   = (const float*)d_in[1];   // (256,256)   fp32
    const float* B   = (const float*)d_in[2];   // (256,)      fp32
    float* out = (float*)d_out;                 // (1024,8,64,256) fp32
    hipLaunchKernelGGL(hippo_legt_kernel, dim3(256), dim3(1024), 0, stream,
                       inp, A, B, out);
}